// Round 11
// baseline (49.286 us; speedup 1.0000x reference)
//
#include <hip/hip_runtime.h>
#include <math.h>

// Problem constants (from reference): B=8, S=4096, D=1024, fp32 in/out.
#define B_   8
#define S_   4096
#define D_   1024
#define RPW  8                  // rows (seq positions) per wave
#define NPB  (S_ / RPW)         // 512 partials per batch
#define NP   (B_ * NPB)         // 4096 partials total

// ws layout: pm [NP] f32 @0, pl [NP] f32 @NP, pacc [NP*D_] f16 @byte 65536
#define PM_OFF    0
#define PL_OFF    NP
#define PACC_BYTE 65536

typedef _Float16 f16x4 __attribute__((ext_vector_type(4)));

// ---------------------------------------------------------------------------
// Pass 1: one pass over data. RPW=8 -> 4096 waves -> 1024 blocks = 4
// blocks/CU (was 2): doubles waves/SIMD for latency hiding. To make the
// live set fit the 128-VGPR tier (lb(256,4)) WITHOUT the R2 spill, the
// pipeline uses 2-row groups: vA[2][4]+vB[2][4]=64 regs + cc 16 + acc 16
// + addr ~15 = ~110 regs. R4/R5 lesson: launch_bounds is mandatory (no-lb
// clamps to 64 VGPR and spills); R3 lesson: no pointers-to-local.
// Partials stored fp16 (|acc| <= ~300, rel err 5e-4 -> ~2e-3 on output).
// ---------------------------------------------------------------------------
__global__ __launch_bounds__(256, 4) void attn_pass1(
    const float* __restrict__ data, const float* __restrict__ crit,
    float* __restrict__ pm, float* __restrict__ pl, f16x4* __restrict__ pacc)
{
    const int lane = threadIdx.x & 63;
    const int gw   = blockIdx.x * 4 + (threadIdx.x >> 6);  // 0..NP-1
    const int b    = gw >> 9;                               // / NPB (=512)
    const int pi   = gw & 511;                              // % NPB
    const int s0   = pi * RPW;

    const float4* c4p = reinterpret_cast<const float4*>(crit + (size_t)b * D_);
    float4 cc[4];
    cc[0] = c4p[0 * 64 + lane];
    cc[1] = c4p[1 * 64 + lane];
    cc[2] = c4p[2 * 64 + lane];
    cc[3] = c4p[3 * 64 + lane];

    const float4* dp = reinterpret_cast<const float4*>(data)
                     + (size_t)(b * S_ + s0) * (D_ / 4);

    float4 a0 = {0,0,0,0}, a1 = {0,0,0,0}, a2 = {0,0,0,0}, a3 = {0,0,0,0};
    float m = -INFINITY, l = 0.f;

    float4 vA[2][4], vB[2][4];

    #define LOADG(V, G)                                                        \
        {                                                                      \
            _Pragma("unroll")                                                  \
            for (int r = 0; r < 2; ++r) {                                      \
                const float4* rp = dp + (size_t)((G) * 2 + r) * (D_ / 4);      \
                V[r][0] = rp[0 * 64 + lane];                                   \
                V[r][1] = rp[1 * 64 + lane];                                   \
                V[r][2] = rp[2 * 64 + lane];                                   \
                V[r][3] = rp[3 * 64 + lane];                                   \
            }                                                                  \
        }

    #define UPD1(A, V, J, F)                                                   \
        A.F = fmaf(A.F, scale, fmaf(p0, V[0][J].F, p1 * V[1][J].F));
    #define UPDA(A, V, J)                                                      \
        UPD1(A, V, J, x) UPD1(A, V, J, y) UPD1(A, V, J, z) UPD1(A, V, J, w)

    // COMPUTE2: 2 row dots -> pack-2 cross-lane reduce (8 DS ops) -> online
    // softmax update.
    #define COMPUTE2(V)                                                        \
        {                                                                      \
            float sc0 = 0.f, sc1 = 0.f;                                        \
            _Pragma("unroll")                                                  \
            for (int j = 0; j < 4; ++j) {                                      \
                sc0 = fmaf(V[0][j].x, cc[j].x, sc0);                           \
                sc0 = fmaf(V[0][j].y, cc[j].y, sc0);                           \
                sc0 = fmaf(V[0][j].z, cc[j].z, sc0);                           \
                sc0 = fmaf(V[0][j].w, cc[j].w, sc0);                           \
                sc1 = fmaf(V[1][j].x, cc[j].x, sc1);                           \
                sc1 = fmaf(V[1][j].y, cc[j].y, sc1);                           \
                sc1 = fmaf(V[1][j].z, cc[j].z, sc1);                           \
                sc1 = fmaf(V[1][j].w, cc[j].w, sc1);                           \
            }                                                                  \
            /* lane keeps row (lane&1), sends the other to lane^1 */           \
            const bool o1 = (lane & 1);                                        \
            float va = o1 ? sc1 : sc0, wa = o1 ? sc0 : sc1;                    \
            va += __shfl_xor(wa, 1, 64);                                       \
            va += __shfl_xor(va, 2, 64);                                       \
            va += __shfl_xor(va, 4, 64);                                       \
            va += __shfl_xor(va, 8, 64);                                       \
            va += __shfl_xor(va, 16, 64);                                      \
            va += __shfl_xor(va, 32, 64);                                      \
            const int base = lane & ~1;                                        \
            const float s0v = __shfl(va, base + 0, 64);                        \
            const float s1v = __shfl(va, base + 1, 64);                        \
            const float gm = fmaxf(s0v, s1v);                                  \
            const float mn = fmaxf(m, gm);                                     \
            const float scale = __expf(m - mn);                                \
            const float p0 = __expf(s0v - mn);                                 \
            const float p1 = __expf(s1v - mn);                                 \
            l = fmaf(l, scale, p0 + p1);                                       \
            UPDA(a0, V, 0) UPDA(a1, V, 1) UPDA(a2, V, 2) UPDA(a3, V, 3)        \
            m = mn;                                                            \
        }

    // Software pipeline over the 4 groups of 2 rows.
    LOADG(vA, 0)
    LOADG(vB, 1)
    COMPUTE2(vA)
    LOADG(vA, 2)
    COMPUTE2(vB)
    LOADG(vB, 3)
    COMPUTE2(vA)
    COMPUTE2(vB)

    #undef LOADG
    #undef COMPUTE2
    #undef UPDA
    #undef UPD1

    // epilogue: convert acc to fp16 and store (4x 8B per lane)
    f16x4* po = pacc + (size_t)gw * (D_ / 4);
    f16x4 h0, h1, h2, h3;
    h0.x = (_Float16)a0.x; h0.y = (_Float16)a0.y;
    h0.z = (_Float16)a0.z; h0.w = (_Float16)a0.w;
    h1.x = (_Float16)a1.x; h1.y = (_Float16)a1.y;
    h1.z = (_Float16)a1.z; h1.w = (_Float16)a1.w;
    h2.x = (_Float16)a2.x; h2.y = (_Float16)a2.y;
    h2.z = (_Float16)a2.z; h2.w = (_Float16)a2.w;
    h3.x = (_Float16)a3.x; h3.y = (_Float16)a3.y;
    h3.z = (_Float16)a3.z; h3.w = (_Float16)a3.w;
    po[0 * 64 + lane] = h0;
    po[1 * 64 + lane] = h1;
    po[2 * 64 + lane] = h2;
    po[3 * 64 + lane] = h3;
    if (lane == 0) { pm[gw] = m; pl[gw] = l; }
}

// ---------------------------------------------------------------------------
// Combine (single kernel): block = (256-col slice, b). 4 waves split the 512
// partials (128 each); lane owns one f16x4 column chunk (8B loads, 512B per
// wave-instruction). pm/pl staged in LDS; mstar/L via fixed-tree reductions;
// 4-wave merge in LDS. Fixed order everywhere -> deterministic.
// ---------------------------------------------------------------------------
__global__ __launch_bounds__(256) void attn_combine(
    const float* __restrict__ pm, const float* __restrict__ pl,
    const f16x4* __restrict__ pacc, float* __restrict__ out)
{
    const int b     = blockIdx.y;
    const int slice = blockIdx.x;            // 0..3 -> cols slice*256..+255
    const int t     = threadIdx.x;           // 0..255
    const int wid   = t >> 6;                // wave 0..3
    const int lane  = t & 63;
    const int c0    = b * NPB;

    __shared__ float  lds_pm[NPB];
    __shared__ float  lds_pl[NPB];
    __shared__ float  red[256];
    __shared__ float4 lds_acc[4][64];
    __shared__ float  lds_mstar, lds_L;

    lds_pm[t]       = pm[c0 + t];
    lds_pm[t + 256] = pm[c0 + t + 256];
    lds_pl[t]       = pl[c0 + t];
    lds_pl[t + 256] = pl[c0 + t + 256];
    __syncthreads();

    // block max over 512 pm values (fixed tree)
    red[t] = fmaxf(lds_pm[t], lds_pm[t + 256]);
    __syncthreads();
    #pragma unroll
    for (int s = 128; s > 0; s >>= 1) {
        if (t < s) red[t] = fmaxf(red[t], red[t + s]);
        __syncthreads();
    }
    if (t == 0) lds_mstar = red[0];
    __syncthreads();
    const float mstar = lds_mstar;

    // block sum of f_k * pl_k (fixed tree)
    red[t] = __expf(lds_pm[t] - mstar) * lds_pl[t]
           + __expf(lds_pm[t + 256] - mstar) * lds_pl[t + 256];
    __syncthreads();
    #pragma unroll
    for (int s = 128; s > 0; s >>= 1) {
        if (t < s) red[t] = red[t] + red[t + s];
        __syncthreads();
    }
    if (t == 0) lds_L = red[0];
    __syncthreads();
    const float inv = 1.f / lds_L;

    // wave wid accumulates k = wid*128 .. +127 for its f16x4 column chunk
    const int col4 = slice * 64 + lane;       // f16x4 index within the row
    float4 acc = {0, 0, 0, 0};
    #pragma unroll 4
    for (int k = 0; k < 128; ++k) {
        const int kk = wid * 128 + k;
        const float f = __expf(lds_pm[kk] - mstar);
        const f16x4 v = pacc[(size_t)(c0 + kk) * (D_ / 4) + col4];
        acc.x = fmaf(f, (float)v.x, acc.x);
        acc.y = fmaf(f, (float)v.y, acc.y);
        acc.z = fmaf(f, (float)v.z, acc.z);
        acc.w = fmaf(f, (float)v.w, acc.w);
    }
    lds_acc[wid][lane] = acc;
    __syncthreads();

    // first 64 threads merge the 4 waves (fixed order) and write out
    if (t < 64) {
        const float4 q0 = lds_acc[0][t];
        const float4 q1 = lds_acc[1][t];
        const float4 q2 = lds_acc[2][t];
        const float4 q3 = lds_acc[3][t];
        float4 o;
        o.x = ((q0.x + q1.x) + (q2.x + q3.x)) * inv;
        o.y = ((q0.y + q1.y) + (q2.y + q3.y)) * inv;
        o.z = ((q0.z + q1.z) + (q2.z + q3.z)) * inv;
        o.w = ((q0.w + q1.w) + (q2.w + q3.w)) * inv;
        reinterpret_cast<float4*>(out)[(size_t)b * (D_ / 4) + slice * 64 + t] = o;
    }
}

extern "C" void kernel_launch(void* const* d_in, const int* in_sizes, int n_in,
                              void* d_out, int out_size, void* d_ws, size_t ws_size,
                              hipStream_t stream)
{
    const float* data = (const float*)d_in[0];   // [B, S, D]
    const float* crit = (const float*)d_in[1];   // [B, D]
    float* ws   = (float*)d_ws;
    float* pm   = ws + PM_OFF;
    float* pl   = ws + PL_OFF;
    f16x4* pacc = reinterpret_cast<f16x4*>((char*)d_ws + PACC_BYTE);
    float* out  = (float*)d_out;

    attn_pass1  <<<NP / 4, 256, 0, stream>>>(data, crit, pm, pl, pacc);
    attn_combine<<<dim3(D_ / 256, B_), 256, 0, stream>>>(pm, pl, pacc, out);
}

// Round 12
// 43.340 us; speedup vs baseline: 1.1372x; 1.1372x over previous
//
#include <hip/hip_runtime.h>
#include <math.h>

// Problem constants (from reference): B=8, S=4096, D=1024, fp32 in/out.
#define B_   8
#define S_   4096
#define D_   1024
#define RPW  8                  // rows (seq positions) per wave
#define NPB  (S_ / RPW)         // 512 partials per batch
#define NP   (B_ * NPB)         // 4096 partials total

// ws layout (float offsets)
#define PM_OFF    0                       // [NP]
#define PL_OFF    NP                      // [NP]
#define PACC_OFF  16384                   // [NP * D_] fp32 (64KB aligned)

// ---------------------------------------------------------------------------
// Pass 1: one pass over data. RPW=8 -> 4096 waves -> 1024 blocks = 4
// blocks/CU grid; VGPR cap 170 (lb(256,3)) -> 3 waves/SIMD co-resident
// (+50% TLP over the 2-wave champion) to hide the serial shuffle-reduce +
// exp chain per group.
//
// Single-variable change from R11's failed attempt: the VGPR budget.
// R11 used lb(256,4) (cap 128) -> suspected re-spill (R2 disease). Live set
// here: vA/vB 64 + cc 16 + acc 16 + addr/temps ~35 = ~130 <= 170. fp32 pacc
// (fp16 reverted). R4/R5 lesson: no-lb clamps to 64 VGPR; R3: no
// pointers-to-local; R8: no LDS/fence extras in this kernel.
// ---------------------------------------------------------------------------
__global__ __launch_bounds__(256, 3) void attn_pass1(
    const float* __restrict__ data, const float* __restrict__ crit,
    float* __restrict__ pm, float* __restrict__ pl, float* __restrict__ pacc)
{
    const int lane = threadIdx.x & 63;
    const int gw   = blockIdx.x * 4 + (threadIdx.x >> 6);  // 0..NP-1
    const int b    = gw >> 9;                               // / NPB (=512)
    const int pi   = gw & 511;                              // % NPB
    const int s0   = pi * RPW;

    const float4* c4p = reinterpret_cast<const float4*>(crit + (size_t)b * D_);
    float4 cc[4];
    cc[0] = c4p[0 * 64 + lane];
    cc[1] = c4p[1 * 64 + lane];
    cc[2] = c4p[2 * 64 + lane];
    cc[3] = c4p[3 * 64 + lane];

    const float4* dp = reinterpret_cast<const float4*>(data)
                     + (size_t)(b * S_ + s0) * (D_ / 4);

    float4 a0 = {0,0,0,0}, a1 = {0,0,0,0}, a2 = {0,0,0,0}, a3 = {0,0,0,0};
    float m = -INFINITY, l = 0.f;

    float4 vA[2][4], vB[2][4];

    #define LOADG(V, G)                                                        \
        {                                                                      \
            _Pragma("unroll")                                                  \
            for (int r = 0; r < 2; ++r) {                                      \
                const float4* rp = dp + (size_t)((G) * 2 + r) * (D_ / 4);      \
                V[r][0] = rp[0 * 64 + lane];                                   \
                V[r][1] = rp[1 * 64 + lane];                                   \
                V[r][2] = rp[2 * 64 + lane];                                   \
                V[r][3] = rp[3 * 64 + lane];                                   \
            }                                                                  \
        }

    #define UPD1(A, V, J, F)                                                   \
        A.F = fmaf(A.F, scale, fmaf(p0, V[0][J].F, p1 * V[1][J].F));
    #define UPDA(A, V, J)                                                      \
        UPD1(A, V, J, x) UPD1(A, V, J, y) UPD1(A, V, J, z) UPD1(A, V, J, w)

    // COMPUTE2: 2 row dots -> pack-2 cross-lane reduce (8 DS ops) -> online
    // softmax update. (Same as R11 -- correctness proven there.)
    #define COMPUTE2(V)                                                        \
        {                                                                      \
            float sc0 = 0.f, sc1 = 0.f;                                        \
            _Pragma("unroll")                                                  \
            for (int j = 0; j < 4; ++j) {                                      \
                sc0 = fmaf(V[0][j].x, cc[j].x, sc0);                           \
                sc0 = fmaf(V[0][j].y, cc[j].y, sc0);                           \
                sc0 = fmaf(V[0][j].z, cc[j].z, sc0);                           \
                sc0 = fmaf(V[0][j].w, cc[j].w, sc0);                           \
                sc1 = fmaf(V[1][j].x, cc[j].x, sc1);                           \
                sc1 = fmaf(V[1][j].y, cc[j].y, sc1);                           \
                sc1 = fmaf(V[1][j].z, cc[j].z, sc1);                           \
                sc1 = fmaf(V[1][j].w, cc[j].w, sc1);                           \
            }                                                                  \
            const bool o1 = (lane & 1);                                        \
            float va = o1 ? sc1 : sc0, wa = o1 ? sc0 : sc1;                    \
            va += __shfl_xor(wa, 1, 64);                                       \
            va += __shfl_xor(va, 2, 64);                                       \
            va += __shfl_xor(va, 4, 64);                                       \
            va += __shfl_xor(va, 8, 64);                                       \
            va += __shfl_xor(va, 16, 64);                                      \
            va += __shfl_xor(va, 32, 64);                                      \
            const int base = lane & ~1;                                        \
            const float s0v = __shfl(va, base + 0, 64);                        \
            const float s1v = __shfl(va, base + 1, 64);                        \
            const float gm = fmaxf(s0v, s1v);                                  \
            const float mn = fmaxf(m, gm);                                     \
            const float scale = __expf(m - mn);                                \
            const float p0 = __expf(s0v - mn);                                 \
            const float p1 = __expf(s1v - mn);                                 \
            l = fmaf(l, scale, p0 + p1);                                       \
            UPDA(a0, V, 0) UPDA(a1, V, 1) UPDA(a2, V, 2) UPDA(a3, V, 3)        \
            m = mn;                                                            \
        }

    // Software pipeline over the 4 groups of 2 rows: next loads always posted.
    LOADG(vA, 0)
    LOADG(vB, 1)
    COMPUTE2(vA)
    LOADG(vA, 2)
    COMPUTE2(vB)
    LOADG(vB, 3)
    COMPUTE2(vA)
    COMPUTE2(vB)

    #undef LOADG
    #undef COMPUTE2
    #undef UPDA
    #undef UPD1

    float4* po = reinterpret_cast<float4*>(pacc) + (size_t)gw * (D_ / 4);
    po[0 * 64 + lane] = a0;
    po[1 * 64 + lane] = a1;
    po[2 * 64 + lane] = a2;
    po[3 * 64 + lane] = a3;
    if (lane == 0) { pm[gw] = m; pl[gw] = l; }
}

// ---------------------------------------------------------------------------
// Combine (single kernel, R10's proven shape at 512 partials): block =
// (256-col slice, b). 4 waves split the 512 partials (128 each); lane owns
// one float4 column -> dwordx4 loads, 1KB/wave/instr. pm/pl staged in LDS;
// mstar/L via fixed-tree reductions; 4-wave merge in LDS. Fixed order
// everywhere -> deterministic.
// ---------------------------------------------------------------------------
__global__ __launch_bounds__(256) void attn_combine(
    const float* __restrict__ pm, const float* __restrict__ pl,
    const float* __restrict__ pacc, float* __restrict__ out)
{
    const int b     = blockIdx.y;
    const int slice = blockIdx.x;            // 0..3 -> cols slice*256..+255
    const int t     = threadIdx.x;           // 0..255
    const int wid   = t >> 6;                // wave 0..3
    const int lane  = t & 63;
    const int c0    = b * NPB;

    __shared__ float  lds_pm[NPB];
    __shared__ float  lds_pl[NPB];
    __shared__ float  red[256];
    __shared__ float4 lds_acc[4][64];
    __shared__ float  lds_mstar, lds_L;

    lds_pm[t]       = pm[c0 + t];
    lds_pm[t + 256] = pm[c0 + t + 256];
    lds_pl[t]       = pl[c0 + t];
    lds_pl[t + 256] = pl[c0 + t + 256];
    __syncthreads();

    // block max over 512 pm values (fixed tree)
    red[t] = fmaxf(lds_pm[t], lds_pm[t + 256]);
    __syncthreads();
    #pragma unroll
    for (int s = 128; s > 0; s >>= 1) {
        if (t < s) red[t] = fmaxf(red[t], red[t + s]);
        __syncthreads();
    }
    if (t == 0) lds_mstar = red[0];
    __syncthreads();
    const float mstar = lds_mstar;

    // block sum of f_k * pl_k (fixed tree)
    red[t] = __expf(lds_pm[t] - mstar) * lds_pl[t]
           + __expf(lds_pm[t + 256] - mstar) * lds_pl[t + 256];
    __syncthreads();
    #pragma unroll
    for (int s = 128; s > 0; s >>= 1) {
        if (t < s) red[t] = red[t] + red[t + s];
        __syncthreads();
    }
    if (t == 0) lds_L = red[0];
    __syncthreads();
    const float inv = 1.f / lds_L;

    // wave wid accumulates k = wid*128 .. +127 for its float4 column
    const int col4 = slice * 64 + lane;       // float4 index within the row
    const float4* pa4 = reinterpret_cast<const float4*>(pacc);
    float4 acc = {0, 0, 0, 0};
    #pragma unroll 8
    for (int k = 0; k < 128; ++k) {
        const int kk = wid * 128 + k;
        const float f = __expf(lds_pm[kk] - mstar);
        const float4 v = pa4[(size_t)(c0 + kk) * (D_ / 4) + col4];
        acc.x = fmaf(f, v.x, acc.x);
        acc.y = fmaf(f, v.y, acc.y);
        acc.z = fmaf(f, v.z, acc.z);
        acc.w = fmaf(f, v.w, acc.w);
    }
    lds_acc[wid][lane] = acc;
    __syncthreads();

    // first 64 threads merge the 4 waves (fixed order) and write out
    if (t < 64) {
        const float4 q0 = lds_acc[0][t];
        const float4 q1 = lds_acc[1][t];
        const float4 q2 = lds_acc[2][t];
        const float4 q3 = lds_acc[3][t];
        float4 o;
        o.x = ((q0.x + q1.x) + (q2.x + q3.x)) * inv;
        o.y = ((q0.y + q1.y) + (q2.y + q3.y)) * inv;
        o.z = ((q0.z + q1.z) + (q2.z + q3.z)) * inv;
        o.w = ((q0.w + q1.w) + (q2.w + q3.w)) * inv;
        reinterpret_cast<float4*>(out)[(size_t)b * (D_ / 4) + slice * 64 + t] = o;
    }
}

extern "C" void kernel_launch(void* const* d_in, const int* in_sizes, int n_in,
                              void* d_out, int out_size, void* d_ws, size_t ws_size,
                              hipStream_t stream)
{
    const float* data = (const float*)d_in[0];   // [B, S, D]
    const float* crit = (const float*)d_in[1];   // [B, D]
    float* ws   = (float*)d_ws;
    float* pm   = ws + PM_OFF;
    float* pl   = ws + PL_OFF;
    float* pacc = ws + PACC_OFF;
    float* out  = (float*)d_out;

    attn_pass1  <<<NP / 4, 256, 0, stream>>>(data, crit, pm, pl, pacc);
    attn_combine<<<dim3(D_ / 256, B_), 256, 0, stream>>>(pm, pl, pacc, out);
}